// Round 4
// baseline (65.137 us; speedup 1.0000x reference)
//
#include <hip/hip_runtime.h>
#include <stdint.h>

#define LL    2000
#define NB    512
#define CIN   32
#define COUT  32
#define TILE  500          // positions per block
#define NT    4            // tiles per n
#define T2    (TILE / 2)   // 250 main threads, 2 positions each

// ---------------- kernel 1: pack weight ternary masks ------------------------
// wb[co*8 + k*2 + {0,1}] = {nz, sign} ci-mask for tap k.
__global__ __launch_bounds__(96) void pack_w_kernel(const float* __restrict__ w,
                                                    uint32_t* __restrict__ wb) {
    int t = threadIdx.x;
    if (t >= COUT * 3) return;
    int co = t / 3, k = t % 3;
    uint32_t nz = 0, sn = 0;
    #pragma unroll
    for (int ci = 0; ci < CIN; ++ci) {
        float v = w[(co * CIN + ci) * 3 + k];
        nz |= ((uint32_t)(v != 0.0f)) << ci;
        sn |= ((uint32_t)(v <  0.0f)) << ci;
    }
    wb[co * 8 + k * 2 + 0] = nz;
    wb[co * 8 + k * 2 + 1] = sn;
}

// dot contribution of one tap: t1 = both-nonzero mask, t2 = differing-sign mask
// tap value = popc(t1) - 2*popc(t2)
#define TAP(nzx, snx, wz, ws) \
    { uint32_t t1 = (nzx) & (wz); uint32_t t2 = ((snx) ^ (ws)) & t1; \
      P += __popc(t1); Q += __popc(t2); }

// ---------------- kernel 2: fused pack + ternary conv (single phase) ----------
// grid = NB*NT. Thread t (<250) packs positions l0+2t, l0+2t+1 across ALL 32 ci
// (32 float2 loads in flight), writes pairs 2t+1, 2t+2 of fin. Threads 250/251
// pack the left/right halo (pairs 0, TILE+1). One barrier. Conv: thread t
// computes 2 positions x 32 co, float2 stores.
// fin pair p <-> position l0+p-1, words {nz, sn} interleaved.
__global__ __launch_bounds__(256, 8) void fused_kernel(const float* __restrict__ x,
                                                       const uint32_t* __restrict__ wb,
                                                       const float* __restrict__ osc,
                                                       const float* __restrict__ lsc,
                                                       float* __restrict__ out) {
    __shared__ uint32_t fin[(TILE + 2) * 2];   // 4016 B

    const int b  = blockIdx.x;
    const int n  = b >> 2;
    const int l0 = (b & 3) * TILE;
    const int t  = threadIdx.x;
    const float* xn = x + (size_t)n * (CIN * LL);

    if (t < T2) {
        const int l = l0 + 2 * t;
        uint32_t nz0 = 0, sn0 = 0, nz1 = 0, sn1 = 0;
        #pragma unroll
        for (int ci = 0; ci < CIN; ++ci) {
            float2 v = *(const float2*)(xn + (size_t)ci * LL + l);
            uint32_t ux = __float_as_uint(v.x), uy = __float_as_uint(v.y);
            uint32_t nx = (ux << 1) ? 1u : 0u;   // v != +-0
            uint32_t ny = (uy << 1) ? 1u : 0u;
            nz0 |= nx << ci;  sn0 |= ((ux >> 31) & nx) << ci;
            nz1 |= ny << ci;  sn1 |= ((uy >> 31) & ny) << ci;
        }
        // pairs 2t+1, 2t+2 -> words 4t+2..4t+5 (8B aligned): two uint2 writes
        uint32_t* dst = &fin[4 * t + 2];
        *(uint2*)(dst + 0) = make_uint2(nz0, sn0);
        *(uint2*)(dst + 2) = make_uint2(nz1, sn1);
    } else if (t == T2 || t == T2 + 1) {
        const bool right = (t == T2 + 1);
        const int l = right ? (l0 + TILE) : (l0 - 1);
        uint32_t nz = 0, sn = 0;
        if (l >= 0 && l < LL) {
            #pragma unroll
            for (int ci = 0; ci < CIN; ++ci) {
                uint32_t u = __float_as_uint(xn[(size_t)ci * LL + l]);
                uint32_t nb = (u << 1) ? 1u : 0u;
                nz |= nb << ci;  sn |= ((u >> 31) & nb) << ci;
            }
        }
        const int p = right ? (TILE + 1) : 0;
        fin[2 * p]     = nz;
        fin[2 * p + 1] = sn;
    }
    __syncthreads();
    if (t >= T2) return;

    const int l = l0 + 2 * t;
    // pairs 2t..2t+3 -> words 4t..4t+7, byte 16t: two aligned uint4 reads
    const uint4 A = *(const uint4*)&fin[4 * t];       // (nz,sn)@l-1, @l
    const uint4 B = *(const uint4*)&fin[4 * t + 4];   // (nz,sn)@l+1, @l+2
    const float2 ls = *(const float2*)(lsc + l);
    float* o = out + (size_t)n * (COUT * LL) + l;

    #pragma unroll 8
    for (int co = 0; co < COUT; ++co) {
        const uint32_t wz0 = wb[co*8+0], ws0 = wb[co*8+1];
        const uint32_t wz1 = wb[co*8+2], ws1 = wb[co*8+3];
        const uint32_t wz2 = wb[co*8+4], ws2 = wb[co*8+5];
        const float os = osc[co];

        int P = 0, Q = 0;
        TAP(A.x, A.y, wz0, ws0) TAP(A.z, A.w, wz1, ws1) TAP(B.x, B.y, wz2, ws2)
        const int d0 = P - 2 * Q;
        P = 0; Q = 0;
        TAP(A.z, A.w, wz0, ws0) TAP(B.x, B.y, wz1, ws1) TAP(B.z, B.w, wz2, ws2)
        const int d1 = P - 2 * Q;

        float2 r;
        r.x = (float)d0 * os * ls.x;
        r.y = (float)d1 * os * ls.y;
        *(float2*)(o + (size_t)co * LL) = r;
    }
}

extern "C" void kernel_launch(void* const* d_in, const int* in_sizes, int n_in,
                              void* d_out, int out_size, void* d_ws, size_t ws_size,
                              hipStream_t stream) {
    const float* x   = (const float*)d_in[0];
    const float* w   = (const float*)d_in[1];
    const float* osc = (const float*)d_in[2];
    const float* lsc = (const float*)d_in[3];
    float* out = (float*)d_out;

    uint32_t* wb = (uint32_t*)d_ws;   // 1 KiB used

    pack_w_kernel<<<1, 96, 0, stream>>>(w, wb);
    fused_kernel<<<NB * NT, 256, 0, stream>>>(x, wb, osc, lsc, out);
}

// Round 5
// 64.960 us; speedup vs baseline: 1.0027x; 1.0027x over previous
//
#include <hip/hip_runtime.h>
#include <stdint.h>

#define LL    2000
#define NB    512
#define CIN   32
#define COUT  32
#define WPOS  128   // positions per wave (64 lanes x 2)
#define BPOS  512   // positions per block (4 waves)
#define NT    4     // blocks per n: ceil(2000/512)

// ---------------- kernel 1: pack weight ternary masks ------------------------
// wb[co*8 + k*2 + {0,1}] = {nz, sign} ci-mask for tap k.
__global__ __launch_bounds__(96) void pack_w_kernel(const float* __restrict__ w,
                                                    uint32_t* __restrict__ wb) {
    int t = threadIdx.x;
    if (t >= COUT * 3) return;
    int co = t / 3, k = t % 3;
    uint32_t nz = 0, sn = 0;
    #pragma unroll
    for (int ci = 0; ci < CIN; ++ci) {
        float v = w[(co * CIN + ci) * 3 + k];
        nz |= ((uint32_t)(v != 0.0f)) << ci;
        sn |= ((uint32_t)(v <  0.0f)) << ci;
    }
    wb[co * 8 + k * 2 + 0] = nz;
    wb[co * 8 + k * 2 + 1] = sn;
}

// tap value = popc(t1) - 2*popc(t2); accumulate P,Q
#define TAP(nzx, snx, wz, ws) \
    { uint32_t t1 = (nzx) & (wz); uint32_t t2 = ((snx) ^ (ws)) & t1; \
      P += __popc(t1); Q += __popc(t2); }

// ---------------- kernel 2: fused pack + conv, barrier-free -------------------
// Wave w of block b covers positions [w0, w0+128). Lane handles l = w0+2*lane
// and l+1. Masks for l-1 / l+2 come from __shfl of neighbor lanes; wave-edge
// halo columns (w0-1, w0+128) are built with one load/lane + 2 ballots
// (lanes 0..31 -> left column ci=lane, lanes 32..63 -> right column ci=lane-32).
// LL is even so a lane's 2 positions are both valid or both OOB.
__global__ __launch_bounds__(256, 4) void fused_kernel(const float* __restrict__ x,
                                                       const uint32_t* __restrict__ wb,
                                                       const float* __restrict__ osc,
                                                       const float* __restrict__ lsc,
                                                       float* __restrict__ out) {
    const int b    = blockIdx.x;
    const int n    = b >> 2;
    const int t    = threadIdx.x;
    const int wid  = t >> 6;
    const int lane = t & 63;
    const int w0   = (b & 3) * BPOS + wid * WPOS;
    const int l    = w0 + 2 * lane;
    const bool valid = (l < LL);
    const float* xn = x + (size_t)n * (CIN * LL);

    // ---- main pack: burst-load 32 float2 (kept in regs), then bit-pack
    const int la = valid ? l : (LL - 2);
    float2 v[CIN];
    #pragma unroll
    for (int ci = 0; ci < CIN; ++ci)
        v[ci] = *(const float2*)(xn + (size_t)ci * LL + la);

    // ---- halo column load (1 float/lane) — overlaps with pack below
    const int hl = w0 - 1, hr = w0 + WPOS;
    const int hc = (lane >= 32) ? hr : hl;
    const bool hv = (hc >= 0) && (hc < LL);
    const uint32_t hu = __float_as_uint(xn[(size_t)(lane & 31) * LL + (hv ? hc : 0)]);

    uint32_t nz0 = 0, sn0 = 0, nz1 = 0, sn1 = 0;
    #pragma unroll
    for (int ci = 0; ci < CIN; ++ci) {
        const uint32_t ux = __float_as_uint(v[ci].x);
        const uint32_t uy = __float_as_uint(v[ci].y);
        const uint32_t nx = (ux << 1) ? 1u : 0u;   // != +-0
        const uint32_t ny = (uy << 1) ? 1u : 0u;
        nz0 |= nx << ci;  sn0 |= ((ux >> 31) & nx) << ci;
        nz1 |= ny << ci;  sn1 |= ((uy >> 31) & ny) << ci;
    }
    if (!valid) { nz0 = 0; sn0 = 0; nz1 = 0; sn1 = 0; }

    // ---- halo ballots (all lanes active up to here)
    const bool hnz = hv && ((hu << 1) != 0);
    const bool hng = hnz && ((hu >> 31) != 0);
    const uint64_t bnz = __ballot(hnz);
    const uint64_t bng = __ballot(hng);
    const uint32_t left_nz  = (uint32_t)bnz,         left_sn  = (uint32_t)bng;
    const uint32_t right_nz = (uint32_t)(bnz >> 32), right_sn = (uint32_t)(bng >> 32);

    // ---- neighbor masks via shuffle
    uint32_t xmn = __shfl_up(nz1, 1u);    // pack(l-1) from lane-1
    uint32_t xms = __shfl_up(sn1, 1u);
    uint32_t xqn = __shfl_down(nz0, 1u);  // pack(l+2) from lane+1
    uint32_t xqs = __shfl_down(sn0, 1u);
    if (lane == 0)  { xmn = left_nz;  xms = left_sn;  }
    if (lane == 63) { xqn = right_nz; xqs = right_sn; }

    if (!valid) return;

    const float2 ls = *(const float2*)(lsc + l);
    float* o = out + (size_t)n * (COUT * LL) + l;

    #pragma unroll 8
    for (int co = 0; co < COUT; ++co) {
        const uint32_t wz0 = wb[co*8+0], ws0 = wb[co*8+1];
        const uint32_t wz1 = wb[co*8+2], ws1 = wb[co*8+3];
        const uint32_t wz2 = wb[co*8+4], ws2 = wb[co*8+5];
        const float os = osc[co];

        int P = 0, Q = 0;
        TAP(xmn, xms, wz0, ws0) TAP(nz0, sn0, wz1, ws1) TAP(nz1, sn1, wz2, ws2)
        const int d0 = P - 2 * Q;
        P = 0; Q = 0;
        TAP(nz0, sn0, wz0, ws0) TAP(nz1, sn1, wz1, ws1) TAP(xqn, xqs, wz2, ws2)
        const int d1 = P - 2 * Q;

        float2 r;
        r.x = (float)d0 * os * ls.x;
        r.y = (float)d1 * os * ls.y;
        *(float2*)(o + (size_t)co * LL) = r;
    }
}

extern "C" void kernel_launch(void* const* d_in, const int* in_sizes, int n_in,
                              void* d_out, int out_size, void* d_ws, size_t ws_size,
                              hipStream_t stream) {
    const float* x   = (const float*)d_in[0];
    const float* w   = (const float*)d_in[1];
    const float* osc = (const float*)d_in[2];
    const float* lsc = (const float*)d_in[3];
    float* out = (float*)d_out;

    uint32_t* wb = (uint32_t*)d_ws;   // 1 KiB used

    pack_w_kernel<<<1, 96, 0, stream>>>(w, wb);
    fused_kernel<<<NB * NT, 256, 0, stream>>>(x, wb, osc, lsc, out);
}

// Round 7
// 53.298 us; speedup vs baseline: 1.2221x; 1.2188x over previous
//
#include <hip/hip_runtime.h>
#include <stdint.h>

#define LL   2000
#define NB   512
#define CIN  32
#define COUT 32
#define TILE 256
#define NT   8    // tiles per n (last covers 208 positions)

typedef float f32x4 __attribute__((ext_vector_type(4)));

// ---------------- kernel 1: pack weight ternary masks ------------------------
// wb[co*8 + k*2 + {0,1}] = {nz, sign} ci-mask for tap k. (words 6,7 unused)
__global__ __launch_bounds__(96) void pack_w_kernel(const float* __restrict__ w,
                                                    uint32_t* __restrict__ wb) {
    int t = threadIdx.x;
    if (t >= COUT * 3) return;
    int co = t / 3, k = t % 3;
    uint32_t nz = 0, sn = 0;
    #pragma unroll
    for (int ci = 0; ci < CIN; ++ci) {
        float v = w[(co * CIN + ci) * 3 + k];
        nz |= ((uint32_t)(v != 0.0f)) << ci;
        sn |= ((uint32_t)(v < 0.0f)) << ci;
    }
    wb[co * 8 + k * 2 + 0] = nz;
    wb[co * 8 + k * 2 + 1] = sn;
}

// ---------------- kernel 2: fused pack + ternary conv -------------------------
// grid = NB*NT blocks, 256 threads. Wave g (=t>>6) packs ci-group [8g,8g+8)
// for 4 positions/thread (8 float4 loads, all kept in flight), then serves
// co-group [8g,8g+8) in conv. Group mask words OR-combined into `fin` between
// two barriers. Pair layout: position p (local, -1..TILE) at pair index p+1,
// words {nz, sign} interleaved.
#define TAP(nzx, snx, wz, ws) \
    { uint32_t t1 = (nzx) & (wz); uint32_t t2 = ((snx) ^ (ws)) & t1; \
      P += __popc(t1); Q += __popc(t2); }

__global__ __launch_bounds__(256, 4) void fused_kernel(const float* __restrict__ x,
                                                       const uint32_t* __restrict__ wb,
                                                       const float* __restrict__ osc,
                                                       const float* __restrict__ lsc,
                                                       float* __restrict__ out) {
    __shared__ uint32_t grp[4][(TILE + 2) * 2];   // 8256 B
    __shared__ uint32_t fin[(TILE + 2) * 2];      // 2064 B

    const int b  = blockIdx.x;
    const int n  = b >> 3;
    const int l0 = (b & 7) * TILE;
    const int t  = threadIdx.x;
    const int g  = __builtin_amdgcn_readfirstlane(t >> 6);  // wave index 0..3
    const int q  = t & 63;
    const float* xn = x + (size_t)n * (CIN * LL);

    // ---- pack main: positions 4q..4q+3, ci in [8g, 8g+8)
    {
        const int lb = l0 + 4 * q;
        uint32_t nz0=0,sn0=0,nz1=0,sn1=0,nz2=0,sn2=0,nz3=0,sn3=0;
        if (lb < LL) {   // 4 | LL, so quads are all-in or all-out
            const uint32_t bit0 = 1u << (8 * g);
            float4 v[8];
            #pragma unroll
            for (int j = 0; j < 8; ++j)
                v[j] = *(const float4*)(xn + (size_t)(8 * g + j) * LL + lb);
            #pragma unroll
            for (int j = 0; j < 8; ++j) {
                const uint32_t m = bit0 << j;
                if (v[j].x != 0.0f) nz0 |= m;   if (v[j].x < 0.0f) sn0 |= m;
                if (v[j].y != 0.0f) nz1 |= m;   if (v[j].y < 0.0f) sn1 |= m;
                if (v[j].z != 0.0f) nz2 |= m;   if (v[j].z < 0.0f) sn2 |= m;
                if (v[j].w != 0.0f) nz3 |= m;   if (v[j].w < 0.0f) sn3 |= m;
            }
        }
        uint32_t* dst = &grp[g][2 * (4 * q + 1)];
        *(uint2*)(dst + 0) = make_uint2(nz0, sn0);
        *(uint2*)(dst + 2) = make_uint2(nz1, sn1);
        *(uint2*)(dst + 4) = make_uint2(nz2, sn2);
        *(uint2*)(dst + 6) = make_uint2(nz3, sn3);
    }
    // ---- halo: threads 0..7 -> (group, left/right)
    if (t < 8) {
        const int  gg    = t & 3;
        const bool right = t >= 4;
        const int  l     = right ? (l0 + TILE) : (l0 - 1);
        uint32_t nz = 0, sn = 0;
        if (l >= 0 && l < LL) {
            #pragma unroll
            for (int j = 0; j < 8; ++j) {
                float v = xn[(size_t)(8 * gg + j) * LL + l];
                if (v != 0.0f) nz |= 1u << (8 * gg + j);
                if (v < 0.0f)  sn |= 1u << (8 * gg + j);
            }
        }
        const int pi = right ? (TILE + 1) : 0;
        grp[gg][2 * pi]     = nz;
        grp[gg][2 * pi + 1] = sn;
    }
    __syncthreads();
    // ---- combine 4 group arrays
    for (int i = t; i < (TILE + 2) * 2; i += 256)
        fin[i] = grp[0][i] | grp[1][i] | grp[2][i] | grp[3][i];
    __syncthreads();

    // ---- conv: positions 4q..4q+3, co in [8g, 8g+8)
    const int l = l0 + 4 * q;
    if (l >= LL) return;
    const uint4 A = *(const uint4*)&fin[8 * q];       // (nz,sn)@p-1, @p
    const uint4 B = *(const uint4*)&fin[8 * q + 4];   // @p+1, @p+2
    const uint4 C = *(const uint4*)&fin[8 * q + 8];   // @p+3, @p+4
    const float4 ls = *(const float4*)(lsc + l);
    float* o = out + (size_t)n * (COUT * LL) + l;

    #pragma unroll
    for (int j = 0; j < 8; ++j) {
        const int co = 8 * g + j;
        const uint32_t wz0 = wb[co*8+0], ws0 = wb[co*8+1];
        const uint32_t wz1 = wb[co*8+2], ws1 = wb[co*8+3];
        const uint32_t wz2 = wb[co*8+4], ws2 = wb[co*8+5];
        const float os = osc[co];

        int P = 0, Q = 0;
        TAP(A.x, A.y, wz0, ws0) TAP(A.z, A.w, wz1, ws1) TAP(B.x, B.y, wz2, ws2)
        const int d0 = P - 2 * Q;
        P = 0; Q = 0;
        TAP(A.z, A.w, wz0, ws0) TAP(B.x, B.y, wz1, ws1) TAP(B.z, B.w, wz2, ws2)
        const int d1 = P - 2 * Q;
        P = 0; Q = 0;
        TAP(B.x, B.y, wz0, ws0) TAP(B.z, B.w, wz1, ws1) TAP(C.x, C.y, wz2, ws2)
        const int d2 = P - 2 * Q;
        P = 0; Q = 0;
        TAP(B.z, B.w, wz0, ws0) TAP(C.x, C.y, wz1, ws1) TAP(C.z, C.w, wz2, ws2)
        const int d3 = P - 2 * Q;

        f32x4 r;
        r.x = (float)d0 * os * ls.x;
        r.y = (float)d1 * os * ls.y;
        r.z = (float)d2 * os * ls.z;
        r.w = (float)d3 * os * ls.w;
        __builtin_nontemporal_store(r, (f32x4*)(o + (size_t)co * LL));
    }
}

extern "C" void kernel_launch(void* const* d_in, const int* in_sizes, int n_in,
                              void* d_out, int out_size, void* d_ws, size_t ws_size,
                              hipStream_t stream) {
    const float* x   = (const float*)d_in[0];
    const float* w   = (const float*)d_in[1];
    const float* osc = (const float*)d_in[2];
    const float* lsc = (const float*)d_in[3];
    float* out = (float*)d_out;

    uint32_t* wb = (uint32_t*)d_ws;   // 1 KiB used

    pack_w_kernel<<<1, 96, 0, stream>>>(w, wb);
    fused_kernel<<<NB * NT, 256, 0, stream>>>(x, wb, osc, lsc, out);
}

// Round 8
// 53.067 us; speedup vs baseline: 1.2274x; 1.0044x over previous
//
#include <hip/hip_runtime.h>
#include <stdint.h>

#define LL   2000
#define NB   512
#define CIN  32
#define COUT 32
#define TILE 256
#define NT   8    // tiles per n (last covers 208 positions)

typedef float f32x4 __attribute__((ext_vector_type(4)));

// ---------------- kernel 1: pack weight ternary masks ------------------------
// wb[co*8 + k*2 + {0,1}] = {nz, sign} ci-mask for tap k. (words 6,7 unused)
__global__ __launch_bounds__(96) void pack_w_kernel(const float* __restrict__ w,
                                                    uint32_t* __restrict__ wb) {
    int t = threadIdx.x;
    if (t >= COUT * 3) return;
    int co = t / 3, k = t % 3;
    uint32_t nz = 0, sn = 0;
    #pragma unroll
    for (int ci = 0; ci < CIN; ++ci) {
        float v = w[(co * CIN + ci) * 3 + k];
        nz |= ((uint32_t)(v != 0.0f)) << ci;
        sn |= ((uint32_t)(v < 0.0f)) << ci;
    }
    wb[co * 8 + k * 2 + 0] = nz;
    wb[co * 8 + k * 2 + 1] = sn;
}

// ---------------- kernel 2: fused pack + ternary conv -------------------------
// grid = NB*NT blocks, 256 threads. Wave g (=t>>6) packs ci-group [8g,8g+8)
// for 4 positions/thread (8 float4 loads held in flight via sched_barrier),
// then serves co-group [8g,8g+8) in conv. Group mask words OR-combined into
// `fin` between two barriers. Pair layout: position p (local, -1..TILE) at
// pair index p+1, words {nz, sign} interleaved.
#define TAP(nzx, snx, wz, ws) \
    { uint32_t t1 = (nzx) & (wz); uint32_t t2 = ((snx) ^ (ws)) & t1; \
      P += __popc(t1); Q += __popc(t2); }

__global__ __launch_bounds__(256, 4) void fused_kernel(const float* __restrict__ x,
                                                       const uint32_t* __restrict__ wb,
                                                       const float* __restrict__ osc,
                                                       const float* __restrict__ lsc,
                                                       float* __restrict__ out) {
    __shared__ uint32_t grp[4][(TILE + 2) * 2];   // 8256 B
    __shared__ uint32_t fin[(TILE + 2) * 2];      // 2064 B

    const int b  = blockIdx.x;
    const int n  = b >> 3;
    const int l0 = (b & 7) * TILE;
    const int t  = threadIdx.x;
    const int g  = __builtin_amdgcn_readfirstlane(t >> 6);  // wave index 0..3
    const int q  = t & 63;
    const float* xn = x + (size_t)n * (CIN * LL);

    // ---- pack main: positions 4q..4q+3, ci in [8g, 8g+8)
    {
        const int lb = l0 + 4 * q;
        uint32_t nz0=0,sn0=0,nz1=0,sn1=0,nz2=0,sn2=0,nz3=0,sn3=0;
        if (lb < LL) {   // 4 | LL, so quads are all-in or all-out
            const uint32_t bit0 = 1u << (8 * g);
            float4 v[8];
            #pragma unroll
            for (int j = 0; j < 8; ++j)
                v[j] = *(const float4*)(xn + (size_t)(8 * g + j) * LL + lb);
            // Pin: keep all 8 global_load_dwordx4 issued before any consumption,
            // so one vmcnt wait covers the burst instead of 8 serialized rounds.
            __builtin_amdgcn_sched_barrier(0);
            #pragma unroll
            for (int j = 0; j < 8; ++j) {
                const uint32_t m = bit0 << j;
                if (v[j].x != 0.0f) nz0 |= m;   if (v[j].x < 0.0f) sn0 |= m;
                if (v[j].y != 0.0f) nz1 |= m;   if (v[j].y < 0.0f) sn1 |= m;
                if (v[j].z != 0.0f) nz2 |= m;   if (v[j].z < 0.0f) sn2 |= m;
                if (v[j].w != 0.0f) nz3 |= m;   if (v[j].w < 0.0f) sn3 |= m;
            }
        }
        uint32_t* dst = &grp[g][2 * (4 * q + 1)];
        *(uint2*)(dst + 0) = make_uint2(nz0, sn0);
        *(uint2*)(dst + 2) = make_uint2(nz1, sn1);
        *(uint2*)(dst + 4) = make_uint2(nz2, sn2);
        *(uint2*)(dst + 6) = make_uint2(nz3, sn3);
    }
    // ---- halo: threads 0..7 -> (group, left/right)
    if (t < 8) {
        const int  gg    = t & 3;
        const bool right = t >= 4;
        const int  l     = right ? (l0 + TILE) : (l0 - 1);
        uint32_t nz = 0, sn = 0;
        if (l >= 0 && l < LL) {
            #pragma unroll
            for (int j = 0; j < 8; ++j) {
                float v = xn[(size_t)(8 * gg + j) * LL + l];
                if (v != 0.0f) nz |= 1u << (8 * gg + j);
                if (v < 0.0f)  sn |= 1u << (8 * gg + j);
            }
        }
        const int pi = right ? (TILE + 1) : 0;
        grp[gg][2 * pi]     = nz;
        grp[gg][2 * pi + 1] = sn;
    }
    __syncthreads();
    // ---- combine 4 group arrays
    for (int i = t; i < (TILE + 2) * 2; i += 256)
        fin[i] = grp[0][i] | grp[1][i] | grp[2][i] | grp[3][i];
    __syncthreads();

    // ---- conv: positions 4q..4q+3, co in [8g, 8g+8)
    const int l = l0 + 4 * q;
    if (l >= LL) return;
    const uint4 A = *(const uint4*)&fin[8 * q];       // (nz,sn)@p-1, @p
    const uint4 B = *(const uint4*)&fin[8 * q + 4];   // @p+1, @p+2
    const uint4 C = *(const uint4*)&fin[8 * q + 8];   // @p+3, @p+4
    const float4 ls = *(const float4*)(lsc + l);
    float* o = out + (size_t)n * (COUT * LL) + l;

    #pragma unroll
    for (int j = 0; j < 8; ++j) {
        const int co = 8 * g + j;
        const uint32_t wz0 = wb[co*8+0], ws0 = wb[co*8+1];
        const uint32_t wz1 = wb[co*8+2], ws1 = wb[co*8+3];
        const uint32_t wz2 = wb[co*8+4], ws2 = wb[co*8+5];
        const float os = osc[co];

        int P = 0, Q = 0;
        TAP(A.x, A.y, wz0, ws0) TAP(A.z, A.w, wz1, ws1) TAP(B.x, B.y, wz2, ws2)
        const int d0 = P - 2 * Q;
        P = 0; Q = 0;
        TAP(A.z, A.w, wz0, ws0) TAP(B.x, B.y, wz1, ws1) TAP(B.z, B.w, wz2, ws2)
        const int d1 = P - 2 * Q;
        P = 0; Q = 0;
        TAP(B.x, B.y, wz0, ws0) TAP(B.z, B.w, wz1, ws1) TAP(C.x, C.y, wz2, ws2)
        const int d2 = P - 2 * Q;
        P = 0; Q = 0;
        TAP(B.z, B.w, wz0, ws0) TAP(C.x, C.y, wz1, ws1) TAP(C.z, C.w, wz2, ws2)
        const int d3 = P - 2 * Q;

        f32x4 r;
        r.x = (float)d0 * os * ls.x;
        r.y = (float)d1 * os * ls.y;
        r.z = (float)d2 * os * ls.z;
        r.w = (float)d3 * os * ls.w;
        __builtin_nontemporal_store(r, (f32x4*)(o + (size_t)co * LL));
    }
}

extern "C" void kernel_launch(void* const* d_in, const int* in_sizes, int n_in,
                              void* d_out, int out_size, void* d_ws, size_t ws_size,
                              hipStream_t stream) {
    const float* x   = (const float*)d_in[0];
    const float* w   = (const float*)d_in[1];
    const float* osc = (const float*)d_in[2];
    const float* lsc = (const float*)d_in[3];
    float* out = (float*)d_out;

    uint32_t* wb = (uint32_t*)d_ws;   // 1 KiB used

    pack_w_kernel<<<1, 96, 0, stream>>>(w, wb);
    fused_kernel<<<NB * NT, 256, 0, stream>>>(x, wb, osc, lsc, out);
}